// Round 2
// baseline (506.919 us; speedup 1.0000x reference)
//
#include <hip/hip_runtime.h>

#define B_ 256
#define T_ 512
#define K_ 128

// DPP quad_perm helpers: xor1 = perm[1,0,3,2] = 0xB1, xor2 = perm[2,3,0,1] = 0x4E
template<int CTRL>
__device__ __forceinline__ int dpp_i(int v) {
  return __builtin_amdgcn_update_dpp(v, v, CTRL, 0xF, 0xF, true);
}
template<int CTRL>
__device__ __forceinline__ float dpp_f(float v) {
  return __int_as_float(dpp_i<CTRL>(__float_as_int(v)));
}

// One block (512 threads) per batch. Thread (j = tid>>2, sub = tid&3) owns
// transitions rows [32*sub, 32*sub+32) of column j in registers. The 4 lanes
// of a quad hold the 4 row-chunk partials of the SAME column -> in-register
// DPP butterfly combine (no LDS partials, no second barrier).
// State double-buffered in LDS (padded chunks, conflict-free float4 reads).
__global__ __launch_bounds__(512) void viterbi_kernel(
    const float* __restrict__ pot,     // B,T,K
    const float* __restrict__ trans,   // K,K
    const int*   __restrict__ lens,    // B
    unsigned char* __restrict__ tags)  // B,T (workspace)
{
  __shared__ __align__(16) float state[2][4 * 36];  // chunk c at offset c*36 (pad 4)
  __shared__ unsigned char bp[T_ - 1][K_];          // 65408 bytes

  const int tid = threadIdx.x;
  const int j   = tid >> 2;
  const int sub = tid & 3;
  const int b   = blockIdx.x;

  // transitions rows [32*sub, 32*sub+32) of column j -> registers
  float tr[32];
  {
    const float* tp = trans + (sub * 32) * K_ + j;
#pragma unroll
    for (int r = 0; r < 32; ++r) tr[r] = tp[r * K_];
  }

  const int L = lens[b];
  const float* potb = pot + (size_t)b * T_ * K_;

  if (sub == 0) state[0][(j >> 5) * 36 + (j & 31)] = potb[j];
  __syncthreads();

  // prefetched emission for step t (loaded one step ahead)
  float xnext = potb[(L > 1 ? K_ : 0) + j];

  int cur = 0;
  for (int t = 1; t < L; ++t) {
    const float x = xnext;
    xnext = potb[(t + 1 < L ? t + 1 : t) * K_ + j];   // prefetch next step

    // partial argmax over my 32 rows, 4 independent ILP chains
    const float4* s4 = reinterpret_cast<const float4*>(&state[cur][sub * 36]);
    float m0 = -INFINITY, m1 = -INFINITY, m2 = -INFINITY, m3 = -INFINITY;
    int   i0 = 0, i1 = 1, i2 = 2, i3 = 3;
#pragma unroll
    for (int r = 0; r < 8; ++r) {
      float4 sv = s4[r];
      float v0 = sv.x + tr[4*r+0]; if (v0 > m0) { m0 = v0; i0 = 4*r+0; }
      float v1 = sv.y + tr[4*r+1]; if (v1 > m1) { m1 = v1; i1 = 4*r+1; }
      float v2 = sv.z + tr[4*r+2]; if (v2 > m2) { m2 = v2; i2 = 4*r+2; }
      float v3 = sv.w + tr[4*r+3]; if (v3 > m3) { m3 = v3; i3 = 4*r+3; }
    }
    // combine chains, exact first-occurrence tie-break (indices interleave)
    float m = m0; int ii = i0;
    if (m1 > m || (m1 == m && i1 < ii)) { m = m1; ii = i1; }
    if (m2 > m || (m2 == m && i2 < ii)) { m = m2; ii = i2; }
    if (m3 > m || (m3 == m && i3 < ii)) { m = m3; ii = i3; }
    ii += sub * 32;   // globalize row index

    // quad butterfly (xor1, xor2) via DPP: all 4 lanes converge to column max
    { float mo = dpp_f<0xB1>(m); int io = dpp_i<0xB1>(ii);
      if (mo > m || (mo == m && io < ii)) { m = mo; ii = io; } }
    { float mo = dpp_f<0x4E>(m); int io = dpp_i<0x4E>(ii);
      if (mo > m || (mo == m && io < ii)) { m = mo; ii = io; } }

    if (sub == 0) {
      state[cur ^ 1][(j >> 5) * 36 + (j & 31)] = x + m;
      bp[t - 1][j] = (unsigned char)ii;
    }
    cur ^= 1;
    __syncthreads();   // single barrier per step (state dbl-buffered)
  }

  // positions p >= L decode to tag 0 (reference semantics)
  { int p = L + tid; if (p < T_) tags[(size_t)b * T_ + p] = 0; }

  // final argmax (first-occurrence) by wave 0, then serial backtrace by lane 0
  if (tid < 64) {
    const float* fs = state[cur];
    int c0 = tid, c1 = tid + 64;
    float m = fs[(c0 >> 5) * 36 + (c0 & 31)]; int ix = c0;
    float v = fs[(c1 >> 5) * 36 + (c1 & 31)];
    if (v > m) { m = v; ix = c1; }
#pragma unroll
    for (int d = 1; d < 64; d <<= 1) {
      float mp = __shfl_xor(m, d);
      int   ip = __shfl_xor(ix, d);
      if (mp > m || (mp == m && ip < ix)) { m = mp; ix = ip; }
    }
    if (tid == 0) {
      int tag = ix;
      unsigned char* tb = tags + (size_t)b * T_;
      tb[L - 1] = (unsigned char)tag;
      for (int p = L - 2; p >= 0; --p) {
        tag = bp[p][tag];
        tb[p] = (unsigned char)tag;
      }
    }
  }
}

// out[b][t][k] = (k == tags[b][t]). One float4 per thread.
__global__ __launch_bounds__(256) void onehot_kernel(
    const unsigned char* __restrict__ tags, float* __restrict__ out)
{
  size_t i = (size_t)blockIdx.x * blockDim.x + threadIdx.x;  // float4 index
  int tag = tags[i >> 5];           // 32 float4s per (b,t) row
  int k   = (int)(i & 31) * 4;
  float4 v;
  v.x = (k     == tag) ? 1.0f : 0.0f;
  v.y = (k + 1 == tag) ? 1.0f : 0.0f;
  v.z = (k + 2 == tag) ? 1.0f : 0.0f;
  v.w = (k + 3 == tag) ? 1.0f : 0.0f;
  reinterpret_cast<float4*>(out)[i] = v;
}

extern "C" void kernel_launch(void* const* d_in, const int* in_sizes, int n_in,
                              void* d_out, int out_size, void* d_ws, size_t ws_size,
                              hipStream_t stream) {
  const float* pot   = (const float*)d_in[0];
  const float* trans = (const float*)d_in[1];
  const int*   lens  = (const int*)d_in[2];
  float* out = (float*)d_out;
  unsigned char* tags = (unsigned char*)d_ws;  // B*T bytes

  viterbi_kernel<<<B_, 512, 0, stream>>>(pot, trans, lens, tags);

  const int n4 = (B_ * T_ * K_) / 4;
  onehot_kernel<<<n4 / 256, 256, 0, stream>>>(tags, out);
}

// Round 3
// 330.207 us; speedup vs baseline: 1.5352x; 1.5352x over previous
//
#include <hip/hip_runtime.h>

#define B_ 256
#define T_ 512
#define K_ 128
#define NTHREADS 256
#define DELTA 0.03125f   // fp32-rounding safety margin on the pruning threshold

// DPP row-rotate max (all-reduce within 16-lane rows via ror 1,2,4,8)
template<int CTRL>
__device__ __forceinline__ float dpp_max(float v) {
  int iv = __float_as_int(v);
  int t = __builtin_amdgcn_update_dpp(iv, iv, CTRL, 0xF, 0xF, false);
  return fmaxf(v, __int_as_float(t));
}

// LDS layout (dynamic, 132608 B):
//   [0, 65536)          float T_lds[128][128]
//   [65536, 130944)     u8 bp[511][128]         (rows only for |C|>=2 steps)
//   [130944, 131968)    u16 code[511]           (i* if |C|==1 else 0xFFFF)
//   [131968, 132480)    u8 tags[512]
//   [132480, 132496)    int scratch (final argmax broadcast)
__global__ __launch_bounds__(NTHREADS) void viterbi_fused(
    const float* __restrict__ pot,     // B,T,K
    const float* __restrict__ trans,   // K,K
    const int*   __restrict__ lens,    // B
    float* __restrict__ out)           // B,T,K one-hot
{
  extern __shared__ __align__(16) char smem[];
  float*          T_lds = (float*)smem;
  unsigned char*  bp    = (unsigned char*)(smem + 65536);
  unsigned short* code  = (unsigned short*)(smem + 130944);
  unsigned char*  tags  = (unsigned char*)(smem + 131968);
  int*            scr   = (int*)(smem + 132480);

  const int tid = threadIdx.x;
  const int b   = blockIdx.x;
  const int L   = lens[b];
  const float* potb = pot + (size_t)b * T_ * K_;

  // ---- Stage transitions to LDS (all 256 threads), tracking min/max ----
  float mn = INFINITY, mx = -INFINITY;
  {
    const float4* t4  = (const float4*)trans;
    float4*       tl4 = (float4*)T_lds;
#pragma unroll
    for (int i = 0; i < 16; ++i) {
      float4 v = t4[i * NTHREADS + tid];
      tl4[i * NTHREADS + tid] = v;
      mn = fminf(mn, fminf(fminf(v.x, v.y), fminf(v.z, v.w)));
      mx = fmaxf(mx, fmaxf(fmaxf(v.x, v.y), fmaxf(v.z, v.w)));
    }
  }
  float* red = (float*)bp;   // bp area unused until forward loop: scratch
  red[tid] = mn; red[NTHREADS + tid] = mx;
  __syncthreads();

  // ---- Forward pass: wave 0 only, zero barriers ----
  if (tid < 64) {
    const int l = tid;
    float rmn = INFINITY, rmx = -INFINITY;
#pragma unroll
    for (int i = 0; i < 4; ++i) rmn = fminf(rmn, red[i * 64 + l]);
#pragma unroll
    for (int i = 0; i < 4; ++i) rmx = fmaxf(rmx, red[256 + i * 64 + l]);
    for (int d = 1; d < 64; d <<= 1) {
      rmn = fminf(rmn, __shfl_xor(rmn, d));
      rmx = fmaxf(rmx, __shfl_xor(rmx, d));
    }
    const float Rng = (rmx - rmn) + DELTA;

    // state in registers: s0 = col l, s1 = col l+64
    float s0 = potb[l], s1 = potb[64 + l];
    float xa0 = potb[K_ + l], xa1 = potb[K_ + 64 + l];  // emission for t=1

    for (int t = 1; t < L; ++t) {
      // prefetch next emission (1 full step of latency hiding)
      const int tn = (t + 1 < L) ? t + 1 : t;
      const float xb0 = potb[tn * K_ + l];
      const float xb1 = potb[tn * K_ + 64 + l];

      // M = max(state) via DPP ror tree + 2 shuffles
      float lm = fmaxf(s0, s1);
      lm = dpp_max<0x121>(lm);               // ror 1
      lm = dpp_max<0x122>(lm);               // ror 2
      lm = dpp_max<0x124>(lm);               // ror 4
      lm = dpp_max<0x128>(lm);               // ror 8
      lm = fmaxf(lm, __shfl_xor(lm, 16));
      lm = fmaxf(lm, __shfl_xor(lm, 32));
      const float thr = lm - Rng;

      // candidate rows: only these can win ANY column (exact dominance prune)
      const unsigned long long b0 = __ballot(s0 >= thr);
      const unsigned long long b1 = __ballot(s1 >= thr);
      const int nc = __popcll(b0) + __popcll(b1);

      float m0 = -INFINITY, m1 = -INFINITY;
      int i0 = 0, i1 = 0;
      unsigned long long bb = b0;
      while (bb) {                            // ascending index order: exact ties
        const int i = __ffsll(bb) - 1; bb &= bb - 1;
        const float si  = __shfl(s0, i);
        const float tv0 = T_lds[i * K_ + l];
        const float tv1 = T_lds[i * K_ + 64 + l];
        const float v0 = si + tv0, v1 = si + tv1;
        if (v0 > m0) { m0 = v0; i0 = i; }
        if (v1 > m1) { m1 = v1; i1 = i; }
      }
      bb = b1;
      while (bb) {
        const int i = __ffsll(bb) - 1; bb &= bb - 1;
        const float si  = __shfl(s1, i);
        const float tv0 = T_lds[(i + 64) * K_ + l];
        const float tv1 = T_lds[(i + 64) * K_ + 64 + l];
        const float v0 = si + tv0, v1 = si + tv1;
        if (v0 > m0) { m0 = v0; i0 = i + 64; }
        if (v1 > m1) { m1 = v1; i1 = i + 64; }
      }

      s0 = xa0 + m0;  s1 = xa1 + m1;          // exact same fp order as reference
      xa0 = xb0;  xa1 = xb1;

      if (nc == 1) {                          // constant bp row: 2-byte record
        if (l == 0) code[t - 1] = (unsigned short)i0;
      } else {
        if (l == 0) code[t - 1] = 0xFFFF;
        bp[(t - 1) * K_ + l]      = (unsigned char)i0;
        bp[(t - 1) * K_ + 64 + l] = (unsigned char)i1;
      }
    }

    // final argmax (first occurrence)
    float bv; int bi;
    if (s1 > s0) { bv = s1; bi = l + 64; } else { bv = s0; bi = l; }
    for (int d = 1; d < 64; d <<= 1) {
      const float ov = __shfl_xor(bv, d);
      const int   oi = __shfl_xor(bi, d);
      if (ov > bv || (ov == bv && oi < bi)) { bv = ov; bi = oi; }
    }
    if (l == 0) { tags[L - 1] = (unsigned char)bi; scr[0] = bi; }
  }
  __syncthreads();

  // ---- Backtrace: parallel segments anchored at |C|==1 steps ----
  const int bestTag = scr[0];
  for (int p = L + tid; p < T_; p += NTHREADS) tags[p] = 0;  // past-end rows -> tag 0
  for (int p = tid; p < L - 1; p += NTHREADS) {
    const unsigned short c = code[p];
    if (c != 0xFFFF) {                 // anchor: tag known regardless of future
      int tg = c;
      tags[p] = (unsigned char)tg;
      int q = p - 1;
      while (q >= 0 && code[q] == 0xFFFF) {
        tg = bp[q * K_ + tg];
        tags[q] = (unsigned char)tg;
        --q;
      }
    }
  }
  if (tid == 0 && L >= 2) {            // top segment from the final argmax
    int tg = bestTag;
    int q = L - 2;
    while (q >= 0 && code[q] == 0xFFFF) {
      tg = bp[q * K_ + tg];
      tags[q] = (unsigned char)tg;
      --q;
    }
  }
  __syncthreads();

  // ---- One-hot write (fused; coalesced float4) ----
  float4* o4 = (float4*)(out + (size_t)b * T_ * K_);
  for (int i = tid; i < T_ * K_ / 4; i += NTHREADS) {
    const int p  = i >> 5;
    const int tg = tags[p];
    const int k  = (i & 31) * 4;
    float4 v;
    v.x = (k     == tg) ? 1.0f : 0.0f;
    v.y = (k + 1 == tg) ? 1.0f : 0.0f;
    v.z = (k + 2 == tg) ? 1.0f : 0.0f;
    v.w = (k + 3 == tg) ? 1.0f : 0.0f;
    o4[i] = v;
  }
}

extern "C" void kernel_launch(void* const* d_in, const int* in_sizes, int n_in,
                              void* d_out, int out_size, void* d_ws, size_t ws_size,
                              hipStream_t stream) {
  const float* pot   = (const float*)d_in[0];
  const float* trans = (const float*)d_in[1];
  const int*   lens  = (const int*)d_in[2];
  float* out = (float*)d_out;

  viterbi_fused<<<B_, NTHREADS, 132608, stream>>>(pot, trans, lens, out);
}

// Round 4
// 328.333 us; speedup vs baseline: 1.5439x; 1.0057x over previous
//
#include <hip/hip_runtime.h>

#define B_ 256
#define T_ 512
#define K_ 128
#define NT 256
#define DELTA 0.03125f   // fp32-rounding safety margin on the pruning threshold

// DPP fmax step. CTRL: 0x121..0x128 = row_ror 1/2/4/8, 0x142 = row_bcast15,
// 0x143 = row_bcast31. bound_ctrl=false + old=src keeps sourceless lanes
// unchanged (fmax(v,v)=v), so the tree is safe for negative values.
template<int CTRL>
__device__ __forceinline__ float dpp_fmax(float v) {
  int iv = __float_as_int(v);
  int t = __builtin_amdgcn_update_dpp(iv, iv, CTRL, 0xF, 0xF, false);
  return fmaxf(v, __int_as_float(t));
}
__device__ __forceinline__ float rlanef(float v, int lane) {
  return __int_as_float(__builtin_amdgcn_readlane(__float_as_int(v), lane));
}

// LDS layout (dynamic, 132608 B):
//   [0, 65536)        float2 Tp[128][64]  -- Tp[i][l] = (T[i][l], T[i][l+64])
//   [65536, 130944)   u8 bp[511][128]     (rows only for |C|>=2 steps)
//   [130944, 131966)  u16 code[511]       (i* if |C|==1 else 0xFFFF)
//   [131968, 132480)  u8 tags[512]
//   [132480, ...)     int scratch
__global__ __launch_bounds__(NT) void viterbi_fused(
    const float* __restrict__ pot,     // B,T,K
    const float* __restrict__ trans,   // K,K
    const int*   __restrict__ lens,    // B
    float* __restrict__ out)           // B,T,K one-hot
{
  extern __shared__ __align__(16) char smem[];
  float2*         Tp   = (float2*)smem;
  unsigned char*  bp   = (unsigned char*)(smem + 65536);
  unsigned short* code = (unsigned short*)(smem + 130944);
  unsigned char*  tags = (unsigned char*)(smem + 131968);
  int*            scr  = (int*)(smem + 132480);

  const int tid = threadIdx.x;
  const int b   = blockIdx.x;
  const int L   = lens[b];
  const float* potb = pot + (size_t)b * T_ * K_;

  // ---- Stage paired transitions to LDS, tracking min/max ----
  float mn = INFINITY, mx = -INFINITY;
  for (int e = tid; e < K_ * 64; e += NT) {
    const int i = e >> 6, l = e & 63;
    const float a = trans[i * K_ + l];
    const float c = trans[i * K_ + l + 64];
    Tp[e] = make_float2(a, c);
    mn = fminf(mn, fminf(a, c));
    mx = fmaxf(mx, fmaxf(a, c));
  }
  float* red = (float*)bp;   // bp area unused until forward loop: scratch
  red[tid] = mn; red[NT + tid] = mx;
  __syncthreads();

  // ---- Forward pass: wave 0 only, zero barriers, no LDS-pipe cross-lane ----
  if (tid < 64) {
    const int l = tid;
    float rmn = INFINITY, rmx = -INFINITY;
#pragma unroll
    for (int i = 0; i < 4; ++i) {
      rmn = fminf(rmn, red[i * 64 + l]);
      rmx = fmaxf(rmx, red[256 + i * 64 + l]);
    }
    for (int d = 1; d < 64; d <<= 1) {
      rmn = fminf(rmn, __shfl_xor(rmn, d));
      rmx = fmaxf(rmx, __shfl_xor(rmx, d));
    }
    const float Rng = (rmx - rmn) + DELTA;

    // state in registers: s0 = col l, s1 = col l+64
    float s0 = potb[l], s1 = potb[64 + l];
    float xa0 = potb[K_ + l], xa1 = potb[K_ + 64 + l];  // emission for t=1

    for (int t = 1; t < L; ++t) {
      // prefetch next emission (off critical path, 1 full step of slack)
      const int tn = (t + 1 < L) ? t + 1 : t;
      const float xb0 = potb[tn * K_ + l];
      const float xb1 = potb[tn * K_ + 64 + l];

      // M = max(state): pure-VALU DPP tree, result in lane 63 -> SGPR
      float lm = fmaxf(s0, s1);
      lm = dpp_fmax<0x121>(lm);   // ror 1
      lm = dpp_fmax<0x122>(lm);   // ror 2
      lm = dpp_fmax<0x124>(lm);   // ror 4
      lm = dpp_fmax<0x128>(lm);   // ror 8  -> 16-row max in all lanes
      lm = dpp_fmax<0x142>(lm);   // row_bcast15
      lm = dpp_fmax<0x143>(lm);   // row_bcast31 -> lane 63 = wave max
      const float M = rlanef(lm, 63);
      const float thr = M - Rng;

      unsigned long long c0m = __ballot(s0 >= thr);
      unsigned long long c1m = __ballot(s1 >= thr);
      int nc = __popcll(c0m) + __popcll(c1m);
      if (nc == 0) { c0m = ~0ull; c1m = ~0ull; nc = 128; }  // unreachable guard

      // first candidate (ascending global index; ties -> first occurrence)
      int c0; float sc;
      if (c0m) { c0 = __ffsll(c0m) - 1; c0m &= c0m - 1; sc = rlanef(s0, c0); }
      else     { int cc = __ffsll(c1m) - 1; c1m &= c1m - 1; sc = rlanef(s1, cc); c0 = cc + 64; }
      const float2 tv = Tp[(c0 << 6) + l];   // issued before branch resolves

      if (nc == 1) {
        // sole candidate wins every column: no compares, no bp row
        s0 = xa0 + (sc + tv.x);
        s1 = xa1 + (sc + tv.y);
        if (l == 0) code[t - 1] = (unsigned short)c0;
      } else {
        float m0 = sc + tv.x, m1 = sc + tv.y;
        int i0 = c0, i1 = c0;
        int rem = nc - 1;
        while (rem--) {
          int c; float sv;
          if (c0m) { c = __ffsll(c0m) - 1; c0m &= c0m - 1; sv = rlanef(s0, c); }
          else     { int cc = __ffsll(c1m) - 1; c1m &= c1m - 1; sv = rlanef(s1, cc); c = cc + 64; }
          const float2 tc = Tp[(c << 6) + l];
          const float v0 = sv + tc.x, v1 = sv + tc.y;
          if (v0 > m0) { m0 = v0; i0 = c; }   // strict >: first-occurrence ties
          if (v1 > m1) { m1 = v1; i1 = c; }
        }
        s0 = xa0 + m0;
        s1 = xa1 + m1;
        bp[(t - 1) * K_ + l]      = (unsigned char)i0;
        bp[(t - 1) * K_ + 64 + l] = (unsigned char)i1;
        if (l == 0) code[t - 1] = 0xFFFF;
      }
      xa0 = xb0; xa1 = xb1;
    }

    // final argmax (first occurrence)
    float bv = s0; int bi = l;
    if (s1 > bv) { bv = s1; bi = l + 64; }
    for (int d = 1; d < 64; d <<= 1) {
      const float ov = __shfl_xor(bv, d);
      const int   oi = __shfl_xor(bi, d);
      if (ov > bv || (ov == bv && oi < bi)) { bv = ov; bi = oi; }
    }
    if (l == 0) { tags[L - 1] = (unsigned char)bi; scr[0] = bi; }
  }
  __syncthreads();

  // ---- Backtrace: parallel segments anchored at |C|==1 steps ----
  const int bestTag = scr[0];
  for (int p = L + tid; p < T_; p += NT) tags[p] = 0;  // past-end -> tag 0
  for (int p = tid; p < L - 1; p += NT) {
    const unsigned short c = code[p];
    if (c != 0xFFFF) {                 // anchor: tag known regardless of future
      int tg = c;
      tags[p] = (unsigned char)tg;
      int q = p - 1;
      while (q >= 0 && code[q] == 0xFFFF) {
        tg = bp[q * K_ + tg];
        tags[q] = (unsigned char)tg;
        --q;
      }
    }
  }
  if (tid == 0 && L >= 2) {            // top segment from the final argmax
    int tg = bestTag;
    int q = L - 2;
    while (q >= 0 && code[q] == 0xFFFF) {
      tg = bp[q * K_ + tg];
      tags[q] = (unsigned char)tg;
      --q;
    }
  }
  __syncthreads();

  // ---- One-hot write (fused; coalesced float4) ----
  float4* o4 = (float4*)(out + (size_t)b * T_ * K_);
  for (int i = tid; i < T_ * K_ / 4; i += NT) {
    const int p  = i >> 5;
    const int tg = tags[p];
    const int k  = (i & 31) * 4;
    float4 v;
    v.x = (k     == tg) ? 1.0f : 0.0f;
    v.y = (k + 1 == tg) ? 1.0f : 0.0f;
    v.z = (k + 2 == tg) ? 1.0f : 0.0f;
    v.w = (k + 3 == tg) ? 1.0f : 0.0f;
    o4[i] = v;
  }
}

extern "C" void kernel_launch(void* const* d_in, const int* in_sizes, int n_in,
                              void* d_out, int out_size, void* d_ws, size_t ws_size,
                              hipStream_t stream) {
  const float* pot   = (const float*)d_in[0];
  const float* trans = (const float*)d_in[1];
  const int*   lens  = (const int*)d_in[2];
  float* out = (float*)d_out;

  viterbi_fused<<<B_, NT, 132608, stream>>>(pot, trans, lens, out);
}

// Round 5
// 311.037 us; speedup vs baseline: 1.6298x; 1.0556x over previous
//
#include <hip/hip_runtime.h>

#define B_ 256
#define T_ 512
#define K_ 128
#define NT 256
#define DELTA 0.03125f   // fp32-rounding safety margin on the pruning threshold

// DPP fmax step. CTRL: 0x121..0x128 = row_ror 1/2/4/8, 0x142 = row_bcast15,
// 0x143 = row_bcast31. bound_ctrl=false + old=src keeps sourceless lanes
// unchanged (fmax(v,v)=v).
template<int CTRL>
__device__ __forceinline__ float dpp_fmax(float v) {
  int iv = __float_as_int(v);
  int t = __builtin_amdgcn_update_dpp(iv, iv, CTRL, 0xF, 0xF, false);
  return fmaxf(v, __int_as_float(t));
}
__device__ __forceinline__ float rlanef(float v, int lane) {
  return __int_as_float(__builtin_amdgcn_readlane(__float_as_int(v), lane));
}
// pop lowest set candidate (ascending global index -> first-occurrence ties)
__device__ __forceinline__ int popcand(unsigned long long& m0, unsigned long long& m1) {
  if (m0) { int c = __ffsll(m0) - 1; m0 &= m0 - 1; return c; }
  int c = __ffsll(m1) - 1; m1 &= m1 - 1; return c + 64;
}

// LDS layout (dynamic, 132608 B):
//   [0, 65536)        float2 Tp[128][64]  -- Tp[i][l] = (T[i][l], T[i][l+64])
//   [65536, 130944)   u8 bp[511][128]     (rows only for |C|>=2 steps)
//   [130944, 131966)  u16 code[511]       (i* if |C|==1 else 0xFFFF)
//   [131968, 132480)  u8 tags[512]
//   [132480, ...)     int scratch
__global__ __launch_bounds__(NT) void viterbi_fused(
    const float* __restrict__ pot,     // B,T,K
    const float* __restrict__ trans,   // K,K
    const int*   __restrict__ lens,    // B
    float* __restrict__ out)           // B,T,K one-hot
{
  extern __shared__ __align__(16) char smem[];
  float2*         Tp   = (float2*)smem;
  unsigned char*  bp   = (unsigned char*)(smem + 65536);
  unsigned short* code = (unsigned short*)(smem + 130944);
  unsigned char*  tags = (unsigned char*)(smem + 131968);
  int*            scr  = (int*)(smem + 132480);

  const int tid = threadIdx.x;
  const int b   = blockIdx.x;
  const int L   = lens[b];
  const float* potb = pot + (size_t)b * T_ * K_;

  // ---- Stage paired transitions to LDS, tracking min/max ----
  float mn = INFINITY, mx = -INFINITY;
  for (int e = tid; e < K_ * 64; e += NT) {
    const int i = e >> 6, ll = e & 63;
    const float a = trans[i * K_ + ll];
    const float c = trans[i * K_ + ll + 64];
    Tp[e] = make_float2(a, c);
    mn = fminf(mn, fminf(a, c));
    mx = fmaxf(mx, fmaxf(a, c));
  }
  float* red = (float*)bp;   // bp area unused until forward loop: scratch
  red[tid] = mn; red[NT + tid] = mx;
  __syncthreads();

  // ---- Forward pass: wave 0 only ----
  if (tid < 64) {
    const int l = tid;
    float rmn = INFINITY, rmx = -INFINITY;
#pragma unroll
    for (int i = 0; i < 4; ++i) {
      rmn = fminf(rmn, red[i * 64 + l]);
      rmx = fmaxf(rmx, red[256 + i * 64 + l]);
    }
    for (int d = 1; d < 64; d <<= 1) {
      rmn = fminf(rmn, __shfl_xor(rmn, d));
      rmx = fmaxf(rmx, __shfl_xor(rmx, d));
    }
    const float Rng = (rmx - rmn) + DELTA;

    // state in registers: s0 = col l, s1 = col l+64
    float s0 = potb[l], s1 = potb[64 + l];

    // 8-deep emission ring (named regs; static indexing only)
    float e0_0, e1_0, e0_1, e1_1, e0_2, e1_2, e0_3, e1_3;
    float e0_4, e1_4, e0_5, e1_5, e0_6, e1_6, e0_7, e1_7;
#define PLOAD(KK)                                                     \
    { int idx = 1 + KK; idx = (idx < L) ? idx : (L - 1);              \
      const float* pp = potb + idx * K_;                              \
      e0_##KK = pp[l]; e1_##KK = pp[64 + l]; }
    PLOAD(0) PLOAD(1) PLOAD(2) PLOAD(3) PLOAD(4) PLOAD(5) PLOAD(6) PLOAD(7)

#define VSTEP(KK, PREF)                                                        \
    {                                                                          \
      float lm = fmaxf(s0, s1);                                                \
      lm = dpp_fmax<0x121>(lm);                                                \
      lm = dpp_fmax<0x122>(lm);                                                \
      lm = dpp_fmax<0x124>(lm);                                                \
      lm = dpp_fmax<0x128>(lm);                                                \
      lm = dpp_fmax<0x142>(lm);                                                \
      lm = dpp_fmax<0x143>(lm);                                                \
      const float M = rlanef(lm, 63);                                          \
      const float thr = M - Rng;                                               \
      unsigned long long c0m = __ballot(s0 >= thr);                            \
      unsigned long long c1m = __ballot(s1 >= thr);                            \
      int nc = __popcll(c0m) + __popcll(c1m);                                  \
      if (nc == 0) { c0m = ~0ull; c1m = ~0ull; nc = 128; }                     \
      const int ca = popcand(c0m, c1m);                                        \
      const float sa = (ca < 64) ? rlanef(s0, ca) : rlanef(s1, ca - 64);       \
      const float2 ta = Tp[(ca << 6) + l];                                     \
      if (nc == 1) {                                                           \
        const float a0 = sa + ta.x, a1 = sa + ta.y;                            \
        s0 = e0_##KK + a0; s1 = e1_##KK + a1;                                  \
        if (l == 0) code[t + KK - 1] = (unsigned short)ca;                     \
      } else {                                                                 \
        const int cb = popcand(c0m, c1m);                                      \
        const float sb = (cb < 64) ? rlanef(s0, cb) : rlanef(s1, cb - 64);     \
        const float2 tb = Tp[(cb << 6) + l];                                   \
        int cc = ca, cd = ca; float scv = sa, sdv = sa;                        \
        float2 tc = ta, td = ta;                                               \
        if (nc >= 3) { cc = popcand(c0m, c1m);                                 \
          scv = (cc < 64) ? rlanef(s0, cc) : rlanef(s1, cc - 64);              \
          tc = Tp[(cc << 6) + l]; }                                            \
        if (nc >= 4) { cd = popcand(c0m, c1m);                                 \
          sdv = (cd < 64) ? rlanef(s0, cd) : rlanef(s1, cd - 64);              \
          td = Tp[(cd << 6) + l]; }                                            \
        float m0 = sa + ta.x, m1 = sa + ta.y; int i0 = ca, i1 = ca;            \
        { const float v0 = sb + tb.x, v1 = sb + tb.y;                          \
          if (v0 > m0) { m0 = v0; i0 = cb; }                                   \
          if (v1 > m1) { m1 = v1; i1 = cb; } }                                 \
        if (nc >= 3) { const float v0 = scv + tc.x, v1 = scv + tc.y;           \
          if (v0 > m0) { m0 = v0; i0 = cc; }                                   \
          if (v1 > m1) { m1 = v1; i1 = cc; } }                                 \
        if (nc >= 4) { const float v0 = sdv + td.x, v1 = sdv + td.y;           \
          if (v0 > m0) { m0 = v0; i0 = cd; }                                   \
          if (v1 > m1) { m1 = v1; i1 = cd; } }                                 \
        int rem = nc - 4;                                                      \
        while (rem-- > 0) {                                                    \
          const int c = popcand(c0m, c1m);                                     \
          const float sv = (c < 64) ? rlanef(s0, c) : rlanef(s1, c - 64);      \
          const float2 tv = Tp[(c << 6) + l];                                  \
          const float v0 = sv + tv.x, v1 = sv + tv.y;                          \
          if (v0 > m0) { m0 = v0; i0 = c; }                                    \
          if (v1 > m1) { m1 = v1; i1 = c; }                                    \
        }                                                                      \
        s0 = e0_##KK + m0; s1 = e1_##KK + m1;                                  \
        bp[(t + KK - 1) * K_ + l]      = (unsigned char)i0;                    \
        bp[(t + KK - 1) * K_ + 64 + l] = (unsigned char)i1;                    \
        if (l == 0) code[t + KK - 1] = 0xFFFF;                                 \
      }                                                                        \
      if (PREF) {                                                              \
        int idx = t + KK + 8; idx = (idx < L) ? idx : (L - 1);                 \
        const float* pp = potb + idx * K_;                                     \
        e0_##KK = pp[l]; e1_##KK = pp[64 + l];                                 \
      }                                                                        \
    }

    int t = 1;
    while (t + 8 <= L) {
      VSTEP(0, true) VSTEP(1, true) VSTEP(2, true) VSTEP(3, true)
      VSTEP(4, true) VSTEP(5, true) VSTEP(6, true) VSTEP(7, true)
      t += 8;
    }
    // guarded static tail (<= 7 steps, ring already holds their emissions)
    if (t + 0 < L) VSTEP(0, false)
    if (t + 1 < L) VSTEP(1, false)
    if (t + 2 < L) VSTEP(2, false)
    if (t + 3 < L) VSTEP(3, false)
    if (t + 4 < L) VSTEP(4, false)
    if (t + 5 < L) VSTEP(5, false)
    if (t + 6 < L) VSTEP(6, false)

    // final argmax (first occurrence)
    float bv = s0; int bi = l;
    if (s1 > bv) { bv = s1; bi = l + 64; }
    for (int d = 1; d < 64; d <<= 1) {
      const float ov = __shfl_xor(bv, d);
      const int   oi = __shfl_xor(bi, d);
      if (ov > bv || (ov == bv && oi < bi)) { bv = ov; bi = oi; }
    }
    if (l == 0) { tags[L - 1] = (unsigned char)bi; scr[0] = bi; }
  }
  __syncthreads();

  // ---- Backtrace: parallel segments anchored at |C|==1 steps ----
  const int bestTag = scr[0];
  for (int p = L + tid; p < T_; p += NT) tags[p] = 0;  // past-end -> tag 0
  for (int p = tid; p < L - 1; p += NT) {
    const unsigned short c = code[p];
    if (c != 0xFFFF) {                 // anchor: tag known regardless of future
      int tg = c;
      tags[p] = (unsigned char)tg;
      int q = p - 1;
      while (q >= 0 && code[q] == 0xFFFF) {
        tg = bp[q * K_ + tg];
        tags[q] = (unsigned char)tg;
        --q;
      }
    }
  }
  if (tid == 0 && L >= 2) {            // top segment from the final argmax
    int tg = bestTag;
    int q = L - 2;
    while (q >= 0 && code[q] == 0xFFFF) {
      tg = bp[q * K_ + tg];
      tags[q] = (unsigned char)tg;
      --q;
    }
  }
  __syncthreads();

  // ---- One-hot write (fused; coalesced float4) ----
  float4* o4 = (float4*)(out + (size_t)b * T_ * K_);
  for (int i = tid; i < T_ * K_ / 4; i += NT) {
    const int p  = i >> 5;
    const int tg = tags[p];
    const int k  = (i & 31) * 4;
    float4 v;
    v.x = (k     == tg) ? 1.0f : 0.0f;
    v.y = (k + 1 == tg) ? 1.0f : 0.0f;
    v.z = (k + 2 == tg) ? 1.0f : 0.0f;
    v.w = (k + 3 == tg) ? 1.0f : 0.0f;
    o4[i] = v;
  }
}

extern "C" void kernel_launch(void* const* d_in, const int* in_sizes, int n_in,
                              void* d_out, int out_size, void* d_ws, size_t ws_size,
                              hipStream_t stream) {
  const float* pot   = (const float*)d_in[0];
  const float* trans = (const float*)d_in[1];
  const int*   lens  = (const int*)d_in[2];
  float* out = (float*)d_out;

  viterbi_fused<<<B_, NT, 132608, stream>>>(pot, trans, lens, out);
}

// Round 8
// 307.838 us; speedup vs baseline: 1.6467x; 1.0104x over previous
//
#include <hip/hip_runtime.h>

#define B_ 256
#define T_ 512
#define K_ 128
#define NT 256
#define DELTA 0.03125f   // fp32-rounding safety margin on the pruning threshold

// DPP fmax step. CTRL: 0x121..0x128 = row_ror 1/2/4/8, 0x142 = row_bcast15,
// 0x143 = row_bcast31. bound_ctrl=false + old=src keeps sourceless lanes
// unchanged (fmax(v,v)=v).
template<int CTRL>
__device__ __forceinline__ float dpp_fmax(float v) {
  int iv = __float_as_int(v);
  int t = __builtin_amdgcn_update_dpp(iv, iv, CTRL, 0xF, 0xF, false);
  return fmaxf(v, __int_as_float(t));
}
__device__ __forceinline__ float rlanef(float v, int lane) {
  return __int_as_float(__builtin_amdgcn_readlane(__float_as_int(v), lane));
}
// pop lowest set candidate (ascending global index -> first-occurrence ties)
__device__ __forceinline__ int popcand(unsigned long long& m0, unsigned long long& m1) {
  if (m0) { int c = __ffsll(m0) - 1; m0 &= m0 - 1; return c; }
  int c = __ffsll(m1) - 1; m1 &= m1 - 1; return c + 64;
}

// Async global load the compiler can't see (no vmcnt bookkeeping by hipcc).
#define GLOAD(dst, p) \
  asm volatile("global_load_dword %0, %1, off" : "=v"(dst) : "v"(p))

// LDS layout (dynamic, 132608 B):
//   [0, 65536)        float2 Tp[128][64]  -- Tp[i][l] = (T[i][l], T[i][l+64])
//   [65536, 130944)   u8 bp[511][128]     (rows only for |C|>=2 steps)
//   [130944, 131966)  u16 code[511]       (i* if |C|==1 else 0xFFFF)
//   [131968, 132480)  u8 tags[512]
//   [132480, ...)     int scratch
__global__ __launch_bounds__(NT) void viterbi_fused(
    const float* __restrict__ pot,     // B,T,K
    const float* __restrict__ trans,   // K,K
    const int*   __restrict__ lens,    // B
    float* __restrict__ out)           // B,T,K one-hot
{
  extern __shared__ __align__(16) char smem[];
  float2*         Tp   = (float2*)smem;
  unsigned char*  bp   = (unsigned char*)(smem + 65536);
  unsigned short* code = (unsigned short*)(smem + 130944);
  unsigned char*  tags = (unsigned char*)(smem + 131968);
  int*            scr  = (int*)(smem + 132480);

  const int tid = threadIdx.x;
  const int b   = blockIdx.x;
  const int L   = lens[b];
  const float* potb = pot + (size_t)b * T_ * K_;
  float4* o4 = (float4*)(out + (size_t)b * T_ * K_);

  // ---- Stage paired transitions to LDS, tracking min/max ----
  float mn = INFINITY, mx = -INFINITY;
  for (int e = tid; e < K_ * 64; e += NT) {
    const int i = e >> 6, ll = e & 63;
    const float a = trans[i * K_ + ll];
    const float c = trans[i * K_ + ll + 64];
    Tp[e] = make_float2(a, c);
    mn = fminf(mn, fminf(a, c));
    mx = fmaxf(mx, fmaxf(a, c));
  }
  float* red = (float*)bp;   // bp area unused until forward loop: scratch
  red[tid] = mn; red[NT + tid] = mx;
  __syncthreads();

  if (tid < 64) {
    // ================= Forward pass: wave 0 =================
    const int l = tid;

    // state cols l, l+64 via asm loads (forward region has NO compiler vmem)
    float s0, s1;
    {
      const float* p0 = potb + l;
      const float* p1 = potb + 64 + l;
      GLOAD(s0, p0); GLOAD(s1, p1);
      asm volatile("s_waitcnt vmcnt(0)" : "+v"(s0), "+v"(s1));
    }

    // 8-deep emission ring: 16 outstanding async loads, manual vmcnt
    float e0_0, e1_0, e0_1, e1_1, e0_2, e1_2, e0_3, e1_3;
    float e0_4, e1_4, e0_5, e1_5, e0_6, e1_6, e0_7, e1_7;
#define PLOAD(KK)                                                       \
    { int idx = 1 + KK; idx = (idx < L) ? idx : (L - 1);                \
      const float* pp = potb + idx * K_ + l;                            \
      GLOAD(e0_##KK, pp); GLOAD(e1_##KK, pp + 64); }
    PLOAD(0) PLOAD(1) PLOAD(2) PLOAD(3) PLOAD(4) PLOAD(5) PLOAD(6) PLOAD(7)

    // threshold range (runs while the ring loads fly)
    float rmn = INFINITY, rmx = -INFINITY;
#pragma unroll
    for (int i = 0; i < 4; ++i) {
      rmn = fminf(rmn, red[i * 64 + l]);
      rmx = fmaxf(rmx, red[256 + i * 64 + l]);
    }
    for (int d = 1; d < 64; d <<= 1) {
      rmn = fminf(rmn, __shfl_xor(rmn, d));
      rmx = fmaxf(rmx, __shfl_xor(rmx, d));
    }
    const float Rng = (rmx - rmn) + DELTA;

#define VSTEP(KK, MAIN)                                                        \
    {                                                                          \
      if (MAIN)                                                                \
        asm volatile("s_waitcnt vmcnt(14)" : "+v"(e0_##KK), "+v"(e1_##KK));    \
      float lm = fmaxf(s0, s1);                                                \
      lm = dpp_fmax<0x121>(lm);                                                \
      lm = dpp_fmax<0x122>(lm);                                                \
      lm = dpp_fmax<0x124>(lm);                                                \
      lm = dpp_fmax<0x128>(lm);                                                \
      lm = dpp_fmax<0x142>(lm);                                                \
      lm = dpp_fmax<0x143>(lm);                                                \
      const float M = rlanef(lm, 63);                                          \
      const float thr = M - Rng;                                               \
      unsigned long long c0m = __ballot(s0 >= thr);                            \
      unsigned long long c1m = __ballot(s1 >= thr);                            \
      int nc = __popcll(c0m) + __popcll(c1m);                                  \
      if (nc == 0) { c0m = ~0ull; c1m = ~0ull; nc = 128; }                     \
      const int ca = popcand(c0m, c1m);                                        \
      const float sa = (ca < 64) ? rlanef(s0, ca) : rlanef(s1, ca - 64);       \
      const float2 ta = Tp[(ca << 6) + l];                                     \
      if (nc == 1) {                                                           \
        const float a0 = sa + ta.x, a1 = sa + ta.y;                            \
        s0 = e0_##KK + a0; s1 = e1_##KK + a1;                                  \
        if (l == 0) code[t + KK - 1] = (unsigned short)ca;                     \
      } else {                                                                 \
        const int cb = popcand(c0m, c1m);                                      \
        const float sb = (cb < 64) ? rlanef(s0, cb) : rlanef(s1, cb - 64);     \
        const float2 tb = Tp[(cb << 6) + l];                                   \
        int cc = ca, cd = ca; float scv = sa, sdv = sa;                        \
        float2 tc = ta, td = ta;                                               \
        if (nc >= 3) { cc = popcand(c0m, c1m);                                 \
          scv = (cc < 64) ? rlanef(s0, cc) : rlanef(s1, cc - 64);              \
          tc = Tp[(cc << 6) + l]; }                                            \
        if (nc >= 4) { cd = popcand(c0m, c1m);                                 \
          sdv = (cd < 64) ? rlanef(s0, cd) : rlanef(s1, cd - 64);              \
          td = Tp[(cd << 6) + l]; }                                            \
        float m0 = sa + ta.x, m1 = sa + ta.y; int i0 = ca, i1 = ca;            \
        { const float v0 = sb + tb.x, v1 = sb + tb.y;                          \
          if (v0 > m0) { m0 = v0; i0 = cb; }                                   \
          if (v1 > m1) { m1 = v1; i1 = cb; } }                                 \
        if (nc >= 3) { const float v0 = scv + tc.x, v1 = scv + tc.y;           \
          if (v0 > m0) { m0 = v0; i0 = cc; }                                   \
          if (v1 > m1) { m1 = v1; i1 = cc; } }                                 \
        if (nc >= 4) { const float v0 = sdv + td.x, v1 = sdv + td.y;           \
          if (v0 > m0) { m0 = v0; i0 = cd; }                                   \
          if (v1 > m1) { m1 = v1; i1 = cd; } }                                 \
        int rem = nc - 4;                                                      \
        while (rem-- > 0) {                                                    \
          const int c = popcand(c0m, c1m);                                     \
          const float sv = (c < 64) ? rlanef(s0, c) : rlanef(s1, c - 64);      \
          const float2 tv = Tp[(c << 6) + l];                                  \
          const float v0 = sv + tv.x, v1 = sv + tv.y;                          \
          if (v0 > m0) { m0 = v0; i0 = c; }                                    \
          if (v1 > m1) { m1 = v1; i1 = c; }                                    \
        }                                                                      \
        s0 = e0_##KK + m0; s1 = e1_##KK + m1;                                  \
        bp[(t + KK - 1) * K_ + l]      = (unsigned char)i0;                    \
        bp[(t + KK - 1) * K_ + 64 + l] = (unsigned char)i1;                    \
        if (l == 0) code[t + KK - 1] = 0xFFFF;                                 \
      }                                                                        \
      if (MAIN) {                                                              \
        int idx = t + KK + 8; idx = (idx < L) ? idx : (L - 1);                 \
        const float* pp = potb + idx * K_ + l;                                 \
        GLOAD(e0_##KK, pp); GLOAD(e1_##KK, pp + 64);                           \
      }                                                                        \
    }

    int t = 1;
    while (t + 8 <= L) {
      VSTEP(0, true) VSTEP(1, true) VSTEP(2, true) VSTEP(3, true)
      VSTEP(4, true) VSTEP(5, true) VSTEP(6, true) VSTEP(7, true)
      t += 8;
    }
    // drain: all ring registers valid after this
    asm volatile("s_waitcnt vmcnt(0)"
      : "+v"(e0_0), "+v"(e1_0), "+v"(e0_1), "+v"(e1_1),
        "+v"(e0_2), "+v"(e1_2), "+v"(e0_3), "+v"(e1_3),
        "+v"(e0_4), "+v"(e1_4), "+v"(e0_5), "+v"(e1_5),
        "+v"(e0_6), "+v"(e1_6), "+v"(e0_7), "+v"(e1_7));
    // guarded static tail (<= 7 steps, emissions already in regs)
    if (t + 0 < L) VSTEP(0, false)
    if (t + 1 < L) VSTEP(1, false)
    if (t + 2 < L) VSTEP(2, false)
    if (t + 3 < L) VSTEP(3, false)
    if (t + 4 < L) VSTEP(4, false)
    if (t + 5 < L) VSTEP(5, false)
    if (t + 6 < L) VSTEP(6, false)

    // final argmax (first occurrence)
    float bv = s0; int bi = l;
    if (s1 > bv) { bv = s1; bi = l + 64; }
    for (int d = 1; d < 64; d <<= 1) {
      const float ov = __shfl_xor(bv, d);
      const int   oi = __shfl_xor(bi, d);
      if (ov > bv || (ov == bv && oi < bi)) { bv = ov; bi = oi; }
    }
    if (l == 0) { tags[L - 1] = (unsigned char)bi; scr[0] = bi; }
  } else {
    // ======== Waves 1-3: write one-hot rows [L, T) concurrently ========
    // (past-end rows decode to tag 0 -> row = e0; independent of forward)
    const int wtid = tid - 64;                 // 0..191
    const int n4 = (T_ - L) * 32;
    for (int e = wtid; e < n4; e += 192) {
      const int row = L + (e >> 5);
      const int q   = e & 31;
      float4 v = make_float4(q == 0 ? 1.0f : 0.0f, 0.0f, 0.0f, 0.0f);
      o4[row * 32 + q] = v;
    }
  }
  __syncthreads();

  // ---- Backtrace: parallel segments anchored at |C|==1 steps ----
  const int bestTag = scr[0];
  for (int p = tid; p < L - 1; p += NT) {
    const unsigned short c = code[p];
    if (c != 0xFFFF) {                 // anchor: tag known regardless of future
      int tg = c;
      tags[p] = (unsigned char)tg;
      int q = p - 1;
      while (q >= 0 && code[q] == 0xFFFF) {
        tg = bp[q * K_ + tg];
        tags[q] = (unsigned char)tg;
        --q;
      }
    }
  }
  if (tid == 0 && L >= 2) {            // top segment from the final argmax
    int tg = bestTag;
    int q = L - 2;
    while (q >= 0 && code[q] == 0xFFFF) {
      tg = bp[q * K_ + tg];
      tags[q] = (unsigned char)tg;
      --q;
    }
  }
  __syncthreads();

  // ---- One-hot write for rows [0, L) (rows >= L already written) ----
  for (int i = tid; i < (L << 5); i += NT) {
    const int p  = i >> 5;
    const int tg = tags[p];
    const int k  = (i & 31) * 4;
    float4 v;
    v.x = (k     == tg) ? 1.0f : 0.0f;
    v.y = (k + 1 == tg) ? 1.0f : 0.0f;
    v.z = (k + 2 == tg) ? 1.0f : 0.0f;
    v.w = (k + 3 == tg) ? 1.0f : 0.0f;
    o4[i] = v;
  }
}

extern "C" void kernel_launch(void* const* d_in, const int* in_sizes, int n_in,
                              void* d_out, int out_size, void* d_ws, size_t ws_size,
                              hipStream_t stream) {
  const float* pot   = (const float*)d_in[0];
  const float* trans = (const float*)d_in[1];
  const int*   lens  = (const int*)d_in[2];
  float* out = (float*)d_out;

  viterbi_fused<<<B_, NT, 132608, stream>>>(pot, trans, lens, out);
}